// Round 2
// baseline (209.367 us; speedup 1.0000x reference)
//
#include <hip/hip_runtime.h>

// sparsegen-lin, lam = 0.5  =>  p = sparsemax(2*x) along rows of length 2048.
// tau solves sum(max(z - tau, 0)) = 1, tau in [max(z)-1, max(z)].
// One 64-lane wave per row; row held in 32 VGPR fp32 per lane.
// 5 bisection iters bracket tau to 2^-5, then 2 Michelot passes
// (tau <- (sum_{z>tau} z - 1)/count) converge it to (near-)exact.

static constexpr float INV_ONE_MINUS_LAM = 2.0f;  // 1/(1-0.5)
static constexpr int ROWLEN = 2048;
static constexpr int WPB = 4;  // waves (rows) per 256-thread block

__global__ __launch_bounds__(256) void sparsegen_lin_kernel(
    const float* __restrict__ in, float* __restrict__ out, int nrows)
{
    const int wave = threadIdx.x >> 6;
    const int lane = threadIdx.x & 63;
    const long long row = (long long)blockIdx.x * WPB + wave;
    if (row >= nrows) return;

    const float* rp = in + row * (long long)ROWLEN;
    float* op = out + row * (long long)ROWLEN;

    // Coalesced load: lane l takes float4 at element i*256 + 4*l.
    float4 z[8];
#pragma unroll
    for (int i = 0; i < 8; ++i) {
        float4 v = *reinterpret_cast<const float4*>(rp + i * 256 + lane * 4);
        v.x *= INV_ONE_MINUS_LAM; v.y *= INV_ONE_MINUS_LAM;
        v.z *= INV_ONE_MINUS_LAM; v.w *= INV_ONE_MINUS_LAM;
        z[i] = v;
    }

    // Row max: 4 parallel accumulators (short dep chain), then butterfly.
    float m0 = -3.4e38f, m1 = -3.4e38f, m2 = -3.4e38f, m3 = -3.4e38f;
#pragma unroll
    for (int i = 0; i < 8; ++i) {
        m0 = fmaxf(m0, z[i].x); m1 = fmaxf(m1, z[i].y);
        m2 = fmaxf(m2, z[i].z); m3 = fmaxf(m3, z[i].w);
    }
    float m = fmaxf(fmaxf(m0, m1), fmaxf(m2, m3));
#pragma unroll
    for (int off = 32; off >= 1; off >>= 1)
        m = fmaxf(m, __shfl_xor(m, off, 64));

    // 5 bisection steps on f(tau) = sum(max(z - tau, 0)) - 1.
    // Invariant: f(lo) >= 0 >= f(hi)  (lo <= tau* <= hi).
    float lo = m - 1.0f;
    float hi = m;
#pragma unroll
    for (int it = 0; it < 5; ++it) {
        const float mid = 0.5f * (lo + hi);
        float s0 = 0.0f, s1 = 0.0f, s2 = 0.0f, s3 = 0.0f;
#pragma unroll
        for (int i = 0; i < 8; ++i) {
            s0 += fmaxf(z[i].x - mid, 0.0f);
            s1 += fmaxf(z[i].y - mid, 0.0f);
            s2 += fmaxf(z[i].z - mid, 0.0f);
            s3 += fmaxf(z[i].w - mid, 0.0f);
        }
        float s = (s0 + s1) + (s2 + s3);
#pragma unroll
        for (int off = 32; off >= 1; off >>= 1)
            s += __shfl_xor(s, off, 64);
        if (s >= 1.0f) lo = mid; else hi = mid;  // wave-uniform branch
    }

    // Two Michelot correction passes from t = lo <= tau*:
    //   S = {z > t} is a superset of the true support; the update
    //   t' = (sum_S z - 1)/|S| satisfies t' <= tau* and converges
    //   (finitely, monotonically) to tau*.
    float t = lo;
#pragma unroll
    for (int pass = 0; pass < 2; ++pass) {
        float s0 = 0.0f, s1 = 0.0f, s2 = 0.0f, s3 = 0.0f;
        float k0 = 0.0f, k1 = 0.0f, k2 = 0.0f, k3 = 0.0f;
#pragma unroll
        for (int i = 0; i < 8; ++i) {
            s0 += (z[i].x > t) ? z[i].x : 0.0f;  k0 += (z[i].x > t) ? 1.0f : 0.0f;
            s1 += (z[i].y > t) ? z[i].y : 0.0f;  k1 += (z[i].y > t) ? 1.0f : 0.0f;
            s2 += (z[i].z > t) ? z[i].z : 0.0f;  k2 += (z[i].z > t) ? 1.0f : 0.0f;
            s3 += (z[i].w > t) ? z[i].w : 0.0f;  k3 += (z[i].w > t) ? 1.0f : 0.0f;
        }
        float s = (s0 + s1) + (s2 + s3);
        float k = (k0 + k1) + (k2 + k3);
#pragma unroll
        for (int off = 32; off >= 1; off >>= 1) {
            s += __shfl_xor(s, off, 64);   // two independent chains —
            k += __shfl_xor(k, off, 64);   // latencies overlap
        }
        t = (s - 1.0f) / fmaxf(k, 1.0f);   // k >= 1 (max element is in S)
    }

    // p = max(z - tau, 0), coalesced float4 stores.
#pragma unroll
    for (int i = 0; i < 8; ++i) {
        float4 p;
        p.x = fmaxf(z[i].x - t, 0.0f);
        p.y = fmaxf(z[i].y - t, 0.0f);
        p.z = fmaxf(z[i].z - t, 0.0f);
        p.w = fmaxf(z[i].w - t, 0.0f);
        *reinterpret_cast<float4*>(op + i * 256 + lane * 4) = p;
    }
}

extern "C" void kernel_launch(void* const* d_in, const int* in_sizes, int n_in,
                              void* d_out, int out_size, void* d_ws, size_t ws_size,
                              hipStream_t stream)
{
    const float* in = (const float*)d_in[0];
    float* out = (float*)d_out;
    const int total = in_sizes[0];
    const int nrows = total / ROWLEN;          // 65536 for the bench shape
    const int blocks = (nrows + WPB - 1) / WPB;
    sparsegen_lin_kernel<<<blocks, 256, 0, stream>>>(in, out, nrows);
}

// Round 4
// 201.856 us; speedup vs baseline: 1.0372x; 1.0372x over previous
//
#include <hip/hip_runtime.h>

// sparsegen-lin, lam = 0.5  =>  p = sparsemax(2*x) along rows of length 2048.
//
// Output is ~99.9% zeros (Gaussian rows, support ~2-5 of 2048), so we split
// directions: (1) hipMemsetAsync zeros d_out at pure-write fill rate
// (~6.7 TB/s measured on this chip); (2) a read-only kernel computes tau per
// row and scatters only the support elements. Mixed-stream 5.2 TB/s becomes
// two direction-pure passes.

static constexpr float INV_ONE_MINUS_LAM = 2.0f;  // 1/(1-0.5)
static constexpr int ROWLEN = 2048;
static constexpr int WPB = 4;  // waves (rows) per 256-thread block

using vfloat4 = __attribute__((ext_vector_type(4))) float;

__global__ __launch_bounds__(256) void sparsegen_tau_scatter_kernel(
    const float* __restrict__ in, float* __restrict__ out, int nrows)
{
    const int wave = threadIdx.x >> 6;
    const int lane = threadIdx.x & 63;
    const long long row = (long long)blockIdx.x * WPB + wave;
    if (row >= nrows) return;

    const float* rp = in + row * (long long)ROWLEN;
    float* op = out + row * (long long)ROWLEN;

    // Coalesced nontemporal loads: lane l takes float4 at element i*256+4*l.
    vfloat4 z[8];
#pragma unroll
    for (int i = 0; i < 8; ++i) {
        vfloat4 v = __builtin_nontemporal_load(
            reinterpret_cast<const vfloat4*>(rp + i * 256 + lane * 4));
        z[i] = v * INV_ONE_MINUS_LAM;
    }

    // Row max: 4 parallel accumulators, then 64-lane butterfly.
    float m0 = -3.4e38f, m1 = -3.4e38f, m2 = -3.4e38f, m3 = -3.4e38f;
#pragma unroll
    for (int i = 0; i < 8; ++i) {
        m0 = fmaxf(m0, z[i].x); m1 = fmaxf(m1, z[i].y);
        m2 = fmaxf(m2, z[i].z); m3 = fmaxf(m3, z[i].w);
    }
    float m = fmaxf(fmaxf(m0, m1), fmaxf(m2, m3));
#pragma unroll
    for (int off = 32; off >= 1; off >>= 1)
        m = fmaxf(m, __shfl_xor(m, off, 64));

    // 5 bisection steps on f(tau) = sum(max(z - tau, 0)) - 1.
    // Invariant: f(lo) >= 0 >= f(hi)  (lo <= tau* <= hi).
    float lo = m - 1.0f;
    float hi = m;
#pragma unroll
    for (int it = 0; it < 5; ++it) {
        const float mid = 0.5f * (lo + hi);
        float s0 = 0.0f, s1 = 0.0f, s2 = 0.0f, s3 = 0.0f;
#pragma unroll
        for (int i = 0; i < 8; ++i) {
            s0 += fmaxf(z[i].x - mid, 0.0f);
            s1 += fmaxf(z[i].y - mid, 0.0f);
            s2 += fmaxf(z[i].z - mid, 0.0f);
            s3 += fmaxf(z[i].w - mid, 0.0f);
        }
        float s = (s0 + s1) + (s2 + s3);
#pragma unroll
        for (int off = 32; off >= 1; off >>= 1)
            s += __shfl_xor(s, off, 64);
        if (s >= 1.0f) lo = mid; else hi = mid;  // wave-uniform branch
    }

    // Two Michelot passes from t = lo <= tau*: S = {z > t} is a superset of
    // the true support; t' = (sum_S z - 1)/|S| <= tau*, monotone convergent.
    float t = lo;
#pragma unroll
    for (int pass = 0; pass < 2; ++pass) {
        float s0 = 0.0f, s1 = 0.0f, s2 = 0.0f, s3 = 0.0f;
        float k0 = 0.0f, k1 = 0.0f, k2 = 0.0f, k3 = 0.0f;
#pragma unroll
        for (int i = 0; i < 8; ++i) {
            s0 += (z[i].x > t) ? z[i].x : 0.0f;  k0 += (z[i].x > t) ? 1.0f : 0.0f;
            s1 += (z[i].y > t) ? z[i].y : 0.0f;  k1 += (z[i].y > t) ? 1.0f : 0.0f;
            s2 += (z[i].z > t) ? z[i].z : 0.0f;  k2 += (z[i].z > t) ? 1.0f : 0.0f;
            s3 += (z[i].w > t) ? z[i].w : 0.0f;  k3 += (z[i].w > t) ? 1.0f : 0.0f;
        }
        float s = (s0 + s1) + (s2 + s3);
        float k = (k0 + k1) + (k2 + k3);
#pragma unroll
        for (int off = 32; off >= 1; off >>= 1) {
            s += __shfl_xor(s, off, 64);   // two independent chains —
            k += __shfl_xor(k, off, 64);   // latencies overlap
        }
        t = (s - 1.0f) / fmaxf(k, 1.0f);   // k >= 1 (max element is in S)
    }

    // Scatter only the support: out was already zeroed by the memset pass.
    // Divergent but tiny (~2-5 stores per row total).
#pragma unroll
    for (int i = 0; i < 8; ++i) {
        const int base = i * 256 + lane * 4;
        if (z[i].x > t) __builtin_nontemporal_store(z[i].x - t, op + base + 0);
        if (z[i].y > t) __builtin_nontemporal_store(z[i].y - t, op + base + 1);
        if (z[i].z > t) __builtin_nontemporal_store(z[i].z - t, op + base + 2);
        if (z[i].w > t) __builtin_nontemporal_store(z[i].w - t, op + base + 3);
    }
}

extern "C" void kernel_launch(void* const* d_in, const int* in_sizes, int n_in,
                              void* d_out, int out_size, void* d_ws, size_t ws_size,
                              hipStream_t stream)
{
    const float* in = (const float*)d_in[0];
    float* out = (float*)d_out;
    const int total = in_sizes[0];
    const int nrows = total / ROWLEN;          // 65536 for the bench shape

    // Pure-write pass: zero the output at fill rate (~6.7 TB/s measured).
    hipMemsetAsync(d_out, 0, (size_t)out_size * sizeof(float), stream);

    // Pure-read pass + sparse scatter.
    const int blocks = (nrows + WPB - 1) / WPB;
    sparsegen_tau_scatter_kernel<<<blocks, 256, 0, stream>>>(in, out, nrows);
}